// Round 2
// baseline (499.648 us; speedup 1.0000x reference)
//
#include <hip/hip_runtime.h>
#include <hip/hip_bf16.h>

// SchNet CFConv fused kernel, MI355X gfx950.
// Shapes: N_ATOMS=10000, K=48 nbrs, F=128 filters, G=25 gaussians.
// Round 2: all tensors are FLOAT32 (per reference dtypes) — round 1's bf16
// cast read f32 bit patterns as bf16 and produced NaN.
//   Kernel A: yfeat = x @ W_in2f           -> d_ws (f32 [N,128])
//   Kernel B: per-atom block, 128 threads:
//     stage1: H[k][f] = ssp(dRe[k,:] . W1[:,f] + b1[f])  (skip if cutoff*mask==0)
//             stored transposed in LDS s_HT[f][k] (k padded to 52)
//     stage2: A2[k][f] = b2[f] + sum_j H[k][j]*W2[j][f]  -- 48 reg accumulators,
//             W2 column streamed (coalesced, L2-resident), H via ds_read_b128 broadcast
//     agg:    acc[f] = sum_k cm[k]*A2[k][f]*yfeat[nbr[k]][f]
//     f2out:  out[f] = ssp(acc . W_f2out[:,f] + b_f2out[f])

#define NA 10000
#define NK 48
#define NF 128
#define NG 25
#define NGP 28   // G padded to multiple of 4 for float4 LDS reads
#define KP 52    // K padded: multiple of 4 (alignment), breaks pow2 bank stride

__device__ __forceinline__ float sspf(float v) {
    // softplus(v) - log(2), numerically stable, fast intrinsics
    return fmaxf(v, 0.0f) + __logf(1.0f + __expf(-fabsf(v))) - 0.69314718056f;
}

__global__ __launch_bounds__(128) void in2f_kernel(
    const float* __restrict__ x,
    const float* __restrict__ Wi,
    float* __restrict__ y)
{
    __shared__ __align__(16) float xs[NF][8];  // [i][atom]
    const int f = threadIdx.x;
    const int n0 = blockIdx.x * 8;
    #pragma unroll
    for (int a = 0; a < 8; ++a)
        xs[f][a] = x[(n0 + a) * NF + f];
    __syncthreads();

    float acc[8];
    #pragma unroll
    for (int a = 0; a < 8; ++a) acc[a] = 0.0f;

    #pragma unroll 4
    for (int i = 0; i < NF; ++i) {
        float w = Wi[i * NF + f];
        const float4* xp = reinterpret_cast<const float4*>(&xs[i][0]);
        float4 x0 = xp[0];
        float4 x1 = xp[1];
        acc[0] = fmaf(x0.x, w, acc[0]);
        acc[1] = fmaf(x0.y, w, acc[1]);
        acc[2] = fmaf(x0.z, w, acc[2]);
        acc[3] = fmaf(x0.w, w, acc[3]);
        acc[4] = fmaf(x1.x, w, acc[4]);
        acc[5] = fmaf(x1.y, w, acc[5]);
        acc[6] = fmaf(x1.z, w, acc[6]);
        acc[7] = fmaf(x1.w, w, acc[7]);
    }
    #pragma unroll
    for (int a = 0; a < 8; ++a)
        y[(n0 + a) * NF + f] = acc[a];
}

__global__ __launch_bounds__(128) void cfconv_kernel(
    const float* __restrict__ dR,
    const float* __restrict__ dRe,
    const float* __restrict__ mask,
    const int*   __restrict__ nbr,
    const float* __restrict__ W1,
    const float* __restrict__ b1,
    const float* __restrict__ W2,
    const float* __restrict__ b2,
    const float* __restrict__ Wf2o,
    const float* __restrict__ bf2o,
    const float* __restrict__ yfeat,
    float*       __restrict__ out)
{
    __shared__ __align__(16) float s_dre[NK * NGP]; // [k][g] padded, 5.25 KB
    __shared__ __align__(16) float s_HT[NF * KP];   // [j][k] padded, 26 KB
    __shared__ __align__(16) float s_y[NF];
    __shared__ float s_cm[NK];
    __shared__ int   s_nb[NK];

    const int f = threadIdx.x;
    const int n = blockIdx.x;

    // ---- preload cutoff*mask and neighbor indices ----
    if (f < NK) {
        float d = dR[n * NK + f];
        float m = mask[n * NK + f];
        s_cm[f] = (d <= 5.0f) ? m : 0.0f;
        s_nb[f] = nbr[n * NK + f];
    }
    // ---- stage dR_expanded into LDS (pad gaussians with 0) ----
    {
        const float* dre = dRe + (size_t)n * (NK * NG);
        for (int i = f; i < NK * NGP; i += NF) {
            int k = i / NGP;
            int g = i - k * NGP;
            s_dre[i] = (g < NG) ? dre[k * NG + g] : 0.0f;
        }
    }
    // ---- preload W1 column + biases into registers ----
    float w1r[NGP];
    #pragma unroll
    for (int g = 0; g < NGP; ++g)
        w1r[g] = (g < NG) ? W1[g * NF + f] : 0.0f;
    const float bb1 = b1[f];
    const float bb2 = b2[f];
    __syncthreads();

    // ---- stage 1: H[k][f] = ssp(dRe[k,:].W1[:,f] + b1[f]), write transposed ----
    for (int k = 0; k < NK; ++k) {
        float sp = 0.0f;
        if (s_cm[k] != 0.0f) {   // block-uniform branch (same LDS value all lanes)
            float a1 = bb1;
            const float4* dp = reinterpret_cast<const float4*>(&s_dre[k * NGP]);
            #pragma unroll
            for (int m = 0; m < NGP / 4; ++m) {
                float4 d4 = dp[m];
                a1 = fmaf(d4.x, w1r[4 * m + 0], a1);
                a1 = fmaf(d4.y, w1r[4 * m + 1], a1);
                a1 = fmaf(d4.z, w1r[4 * m + 2], a1);
                a1 = fmaf(d4.w, w1r[4 * m + 3], a1);
            }
            sp = sspf(a1);
        }
        s_HT[f * KP + k] = sp;
    }
    __syncthreads();

    // ---- stage 2: A2[k][f] = b2[f] + sum_j H[k][j]*W2[j][f] ----
    float acc2[NK];
    #pragma unroll
    for (int k = 0; k < NK; ++k) acc2[k] = bb2;

    #pragma unroll 2
    for (int j = 0; j < NF; ++j) {
        float w = W2[j * NF + f];
        const float4* hp = reinterpret_cast<const float4*>(&s_HT[j * KP]);
        #pragma unroll
        for (int m = 0; m < NK / 4; ++m) {
            float4 h = hp[m];
            acc2[4 * m + 0] = fmaf(h.x, w, acc2[4 * m + 0]);
            acc2[4 * m + 1] = fmaf(h.y, w, acc2[4 * m + 1]);
            acc2[4 * m + 2] = fmaf(h.z, w, acc2[4 * m + 2]);
            acc2[4 * m + 3] = fmaf(h.w, w, acc2[4 * m + 3]);
        }
    }

    // ---- aggregate over neighbors: sum_k cm[k]*A2[k][f]*yfeat[nbr[k]][f] ----
    float agg = 0.0f;
    #pragma unroll
    for (int k = 0; k < NK; ++k) {
        float yv = yfeat[(size_t)s_nb[k] * NF + f];
        agg = fmaf(s_cm[k] * acc2[k], yv, agg);
    }

    // ---- f2out: out = ssp(agg . Wf2o + b) ----
    s_y[f] = agg;
    const float bo = bf2o[f];
    __syncthreads();
    float o = bo;
    const float4* yp = reinterpret_cast<const float4*>(s_y);
    #pragma unroll 4
    for (int m = 0; m < NF / 4; ++m) {
        float4 y4 = yp[m];
        o = fmaf(y4.x, Wf2o[(4 * m + 0) * NF + f], o);
        o = fmaf(y4.y, Wf2o[(4 * m + 1) * NF + f], o);
        o = fmaf(y4.z, Wf2o[(4 * m + 2) * NF + f], o);
        o = fmaf(y4.w, Wf2o[(4 * m + 3) * NF + f], o);
    }
    out[n * NF + f] = sspf(o);
}

extern "C" void kernel_launch(void* const* d_in, const int* in_sizes, int n_in,
                              void* d_out, int out_size, void* d_ws, size_t ws_size,
                              hipStream_t stream)
{
    const float* x    = (const float*)d_in[0];
    const float* dR   = (const float*)d_in[1];
    const float* dRe  = (const float*)d_in[2];
    const float* mask = (const float*)d_in[3];
    const int*   nbr  = (const int*)d_in[4];
    const float* W1   = (const float*)d_in[5];
    const float* b1   = (const float*)d_in[6];
    const float* W2   = (const float*)d_in[7];
    const float* b2   = (const float*)d_in[8];
    const float* Wi2f = (const float*)d_in[9];
    const float* Wf2o = (const float*)d_in[10];
    const float* bf2o = (const float*)d_in[11];
    float* out = (float*)d_out;
    float* yfeat = (float*)d_ws;   // N*F f32 = 5.12 MB scratch

    in2f_kernel<<<NA / 8, NF, 0, stream>>>(x, Wi2f, yfeat);
    cfconv_kernel<<<NA, NF, 0, stream>>>(dR, dRe, mask, nbr, W1, b1, W2, b2,
                                         Wf2o, bf2o, yfeat, out);
}

// Round 3
// 197.042 us; speedup vs baseline: 2.5357x; 2.5357x over previous
//
#include <hip/hip_runtime.h>
#include <hip/hip_bf16.h>

// SchNet CFConv, MI355X gfx950 — round 3: bf16 MFMA (16x16x32) for all GEMM stages.
// N=10000 atoms, K=48 nbrs, F=128, G=25. All float tensors f32; absmax threshold
// 0.251 (2% of max|ref|) leaves room for bf16 compute with f32 accumulate.
//
// d_ws layout (unsigned short elements):
//   [0      .. 4096 )  W1T  bf16 [128 f][32 gpad]   (transposed, g>=25 zero)
//   [4096   .. 20480)  W2T  bf16 [128 h][128 j]     (transposed)
//   [20480  .. 36864)  WiT  bf16 [128 f][128 i]     (transposed)
//   [36864  .. +1.28M) yfeatb bf16 [10000][128]     (x @ W_in2f, L2-resident)
// Total 2.63 MB (round-2 proved >=5.12 MB available).
//
// cfconv: 1 atom/block, 256 thr (4 waves), wave w owns N-tiles {2w,2w+1}.
//   stage1: H = ssp(dRe_pad[48x32] @ W1 + b1) -> LDS bf16 [48][136] (pad: ~2-way)
//   stage2: A2 = H @ W2 (+b2 in epilogue), B-frags direct global->VGPR (L2)
//   gather: y[h] = sum_k cm[k]*(A2[k][h]+b2[h])*yfeat[nbr[k]][h], shfl-reduce
//   f2out : out = ssp(y @ Wf2o + b) vector f32 (0.33 GF total)

#define NA 10000
#define NK 48
#define NF 128
#define DREP 40   // dRe LDS row pad (bf16): start-bank spread -> ~2-way (free)
#define HP   136  // H   LDS row pad (bf16): 272 B rows -> ~2-way (free)

typedef __bf16 bf16x8 __attribute__((ext_vector_type(8)));
typedef float  f32x4  __attribute__((ext_vector_type(4)));

__device__ __forceinline__ unsigned short f2bs(float x) {
    return __builtin_bit_cast(unsigned short, (__bf16)x);
}
__device__ __forceinline__ float bs2f(unsigned short u) {
    return (float)__builtin_bit_cast(__bf16, u);
}
__device__ __forceinline__ float sspf(float v) {
    return fmaxf(v, 0.0f) + __logf(1.0f + __expf(-fabsf(v))) - 0.69314718056f;
}

// ---- setup: transpose-convert weights to bf16 in d_ws ----
__global__ __launch_bounds__(256) void prep_weights(
    const float* __restrict__ W1,
    const float* __restrict__ W2,
    const float* __restrict__ Wi,
    unsigned short* __restrict__ wsb)
{
    int i = blockIdx.x * 256 + threadIdx.x;
    if (i < 4096) {                       // W1T[f][g], g padded to 32
        int f = i >> 5, g = i & 31;
        wsb[i] = (g < 25) ? f2bs(W1[g * NF + f]) : (unsigned short)0;
    } else if (i < 20480) {               // W2T[h][j]
        int j = i - 4096; int h = j >> 7, k = j & 127;
        wsb[i] = f2bs(W2[k * NF + h]);
    } else if (i < 36864) {               // WiT[f][i]
        int j = i - 20480; int f = j >> 7, k = j & 127;
        wsb[i] = f2bs(Wi[k * NF + f]);
    }
}

// ---- in2f: yfeatb = bf16( x @ W_in2f ), MFMA, 64 rows/block ----
__global__ __launch_bounds__(256) void in2f_mfma(
    const float* __restrict__ x,
    const unsigned short* __restrict__ WiT,
    unsigned short* __restrict__ yfeatb)
{
    const int tid = threadIdx.x;
    const int w = tid >> 6;
    const int lane = tid & 63;
    const int r = lane & 15;
    const int q = lane >> 4;
    const int m0 = blockIdx.x * 64 + w * 16;
    const int row = m0 + r;
    const bool rv = (row < NA);

    f32x4 acc[8];
    #pragma unroll
    for (int nt = 0; nt < 8; ++nt) { acc[nt][0]=0.f; acc[nt][1]=0.f; acc[nt][2]=0.f; acc[nt][3]=0.f; }

    #pragma unroll
    for (int ks = 0; ks < 4; ++ks) {
        bf16x8 a;
        if (rv) {
            const float4* xp = (const float4*)(x + (size_t)row * NF + ks * 32 + q * 8);
            float4 v0 = xp[0], v1 = xp[1];
            a[0]=(__bf16)v0.x; a[1]=(__bf16)v0.y; a[2]=(__bf16)v0.z; a[3]=(__bf16)v0.w;
            a[4]=(__bf16)v1.x; a[5]=(__bf16)v1.y; a[6]=(__bf16)v1.z; a[7]=(__bf16)v1.w;
        } else {
            #pragma unroll
            for (int j = 0; j < 8; ++j) a[j] = (__bf16)0.0f;
        }
        #pragma unroll
        for (int nt = 0; nt < 8; ++nt) {
            bf16x8 b = *(const bf16x8*)(WiT + (nt * 16 + r) * NF + ks * 32 + q * 8);
            acc[nt] = __builtin_amdgcn_mfma_f32_16x16x32_bf16(a, b, acc[nt], 0, 0, 0);
        }
    }
    #pragma unroll
    for (int nt = 0; nt < 8; ++nt) {
        #pragma unroll
        for (int reg = 0; reg < 4; ++reg) {
            int orow = m0 + q * 4 + reg;
            if (orow < NA)
                yfeatb[(size_t)orow * NF + nt * 16 + r] = f2bs(acc[nt][reg]);
        }
    }
}

// ---- cfconv: MFMA filter net + gather/aggregate + f2out ----
__global__ __launch_bounds__(256) void cfconv_mfma(
    const float* __restrict__ dR,
    const float* __restrict__ dRe,
    const float* __restrict__ mask,
    const int*   __restrict__ nbr,
    const float* __restrict__ b1,
    const float* __restrict__ b2,
    const float* __restrict__ Wf2o,
    const float* __restrict__ bf2o,
    const unsigned short* __restrict__ W1T,
    const unsigned short* __restrict__ W2T,
    const unsigned short* __restrict__ yfeatb,
    float* __restrict__ out)
{
    __shared__ __align__(16) unsigned short s_dre[NK * DREP]; // 3840 B
    __shared__ __align__(16) unsigned short s_H[NK * HP];     // 13056 B
    __shared__ __align__(16) float s_y[NF];
    __shared__ __align__(16) float s_part[256];
    __shared__ float s_cm[NK];
    __shared__ int   s_nb[NK];

    const int tid = threadIdx.x;
    const int n = blockIdx.x;
    const int w = tid >> 6;
    const int lane = tid & 63;
    const int r = lane & 15;
    const int q = lane >> 4;
    const int nt0 = w * 2;        // this wave's two N-tiles

    // ---- staging ----
    {
        unsigned int* z = (unsigned int*)s_dre;
        for (int i = tid; i < NK * DREP / 2; i += 256) z[i] = 0u;
    }
    if (tid < NK) {
        float d = dR[n * NK + tid];
        float m = mask[n * NK + tid];
        s_cm[tid] = (d <= 5.0f) ? m : 0.0f;
        s_nb[tid] = nbr[n * NK + tid] * NF;
    }
    __syncthreads();
    {
        const float* dre = dRe + (size_t)n * (NK * 25);
        for (int i = tid; i < NK * 25; i += 256) {
            int k = i / 25;
            int g = i - k * 25;
            s_dre[k * DREP + g] = f2bs(dre[i]);
        }
    }
    __syncthreads();

    // ---- stage 1: H = ssp(dRe @ W1 + b1) ----
    const float bias1a = b1[nt0 * 16 + r];
    const float bias1b = b1[nt0 * 16 + 16 + r];
    {
        bf16x8 bfr[2];
        bfr[0] = *(const bf16x8*)(W1T + ((nt0    ) * 16 + r) * 32 + q * 8);
        bfr[1] = *(const bf16x8*)(W1T + ((nt0 + 1) * 16 + r) * 32 + q * 8);
        #pragma unroll
        for (int mt = 0; mt < 3; ++mt) {
            bf16x8 a = *(const bf16x8*)(&s_dre[(mt * 16 + r) * DREP + q * 8]);
            #pragma unroll
            for (int t = 0; t < 2; ++t) {
                f32x4 zf; zf[0]=0.f; zf[1]=0.f; zf[2]=0.f; zf[3]=0.f;
                f32x4 h = __builtin_amdgcn_mfma_f32_16x16x32_bf16(a, bfr[t], zf, 0, 0, 0);
                float bia = t ? bias1b : bias1a;
                #pragma unroll
                for (int reg = 0; reg < 4; ++reg) {
                    int k = mt * 16 + q * 4 + reg;
                    int f = (nt0 + t) * 16 + r;
                    s_H[k * HP + f] = f2bs(sspf(h[reg] + bia));
                }
            }
        }
    }
    __syncthreads();

    // ---- stage 2: A2 = H @ W2 (bias in epilogue) ----
    const float bias2a = b2[nt0 * 16 + r];
    const float bias2b = b2[nt0 * 16 + 16 + r];
    f32x4 acc[3][2];
    #pragma unroll
    for (int mt = 0; mt < 3; ++mt)
        #pragma unroll
        for (int t = 0; t < 2; ++t) { acc[mt][t][0]=0.f; acc[mt][t][1]=0.f; acc[mt][t][2]=0.f; acc[mt][t][3]=0.f; }

    bf16x8 bw[2][4];
    #pragma unroll
    for (int t = 0; t < 2; ++t)
        #pragma unroll
        for (int ks = 0; ks < 4; ++ks)
            bw[t][ks] = *(const bf16x8*)(W2T + ((nt0 + t) * 16 + r) * NF + ks * 32 + q * 8);

    #pragma unroll
    for (int ks = 0; ks < 4; ++ks) {
        #pragma unroll
        for (int mt = 0; mt < 3; ++mt) {
            bf16x8 a = *(const bf16x8*)(&s_H[(mt * 16 + r) * HP + ks * 32 + q * 8]);
            #pragma unroll
            for (int t = 0; t < 2; ++t)
                acc[mt][t] = __builtin_amdgcn_mfma_f32_16x16x32_bf16(a, bw[t][ks], acc[mt][t], 0, 0, 0);
        }
    }

    // ---- gather + masked aggregation over neighbors ----
    float part0 = 0.f, part1 = 0.f;
    const int h0 = nt0 * 16 + r;
    #pragma unroll
    for (int mt = 0; mt < 3; ++mt) {
        #pragma unroll
        for (int reg = 0; reg < 4; ++reg) {
            int k = mt * 16 + q * 4 + reg;
            float cmk = s_cm[k];
            int base = s_nb[k];
            part0 += cmk * (acc[mt][0][reg] + bias2a) * bs2f(yfeatb[base + h0]);
            part1 += cmk * (acc[mt][1][reg] + bias2b) * bs2f(yfeatb[base + h0 + 16]);
        }
    }
    part0 += __shfl_xor(part0, 16);
    part0 += __shfl_xor(part0, 32);
    part1 += __shfl_xor(part1, 16);
    part1 += __shfl_xor(part1, 32);
    if (q == 0) {
        s_y[h0] = part0;
        s_y[h0 + 16] = part1;
    }
    __syncthreads();

    // ---- f2out: out = ssp(y @ Wf2o + b), split i-range over 2 half-blocks ----
    {
        int f = tid & 127;
        int half = tid >> 7;
        float o = 0.f;
        const float* wp = Wf2o + (size_t)(half * 64) * NF + f;
        const float* yp = s_y + half * 64;
        #pragma unroll 8
        for (int i = 0; i < 64; ++i)
            o = fmaf(yp[i], wp[(size_t)i * NF], o);
        s_part[tid] = o;
    }
    __syncthreads();
    if (tid < NF)
        out[(size_t)n * NF + tid] = sspf(s_part[tid] + s_part[tid + 128] + bf2o[tid]);
}

extern "C" void kernel_launch(void* const* d_in, const int* in_sizes, int n_in,
                              void* d_out, int out_size, void* d_ws, size_t ws_size,
                              hipStream_t stream)
{
    const float* x    = (const float*)d_in[0];
    const float* dR   = (const float*)d_in[1];
    const float* dRe  = (const float*)d_in[2];
    const float* mask = (const float*)d_in[3];
    const int*   nbr  = (const int*)d_in[4];
    const float* W1   = (const float*)d_in[5];
    const float* b1   = (const float*)d_in[6];
    const float* W2   = (const float*)d_in[7];
    const float* b2   = (const float*)d_in[8];
    const float* Wi2f = (const float*)d_in[9];
    const float* Wf2o = (const float*)d_in[10];
    const float* bf2o = (const float*)d_in[11];
    float* out = (float*)d_out;

    unsigned short* wsb = (unsigned short*)d_ws;
    unsigned short* W1T    = wsb;            // 4096 elems
    unsigned short* W2T    = wsb + 4096;     // 16384 elems
    unsigned short* WiT    = wsb + 20480;    // 16384 elems
    unsigned short* yfeatb = wsb + 36864;    // 1,280,000 elems

    prep_weights<<<144, 256, 0, stream>>>(W1, W2, Wi2f, wsb);
    in2f_mfma<<<157, 256, 0, stream>>>(x, WiT, yfeatb);
    cfconv_mfma<<<NA, 256, 0, stream>>>(dR, dRe, mask, nbr, b1, b2, Wf2o, bf2o,
                                        W1T, W2T, yfeatb, out);
}